// Round 6
// baseline (571.469 us; speedup 1.0000x reference)
//
#include <hip/hip_runtime.h>
#include <hip/hip_bf16.h>

#define Bn 32
#define Ln 2048
#define Dn 768
#define Hn 512
#define Mn (Bn*Ln)
#define EPSC 1e-5f

// ws float-offset layout (first 128 KB), then byte regions
#define OFF_S1   0        // [512] masked sum(h)
#define OFF_S2   512      // [512] masked sum(h^2)
#define OFF_CNT  2048     // [32] per-batch counts
#define OFF_PH   2304     // [32*512] pooled relu(BN(h)) sums (atomic)
#define OFF_W1T_BYTES  131072   // bf16 W1^T [512][768] = 786 KB
#define OFF_H_BYTES    1048576  // tiled bf16 h buffer, 64 MB

typedef __attribute__((ext_vector_type(8))) short bf16x8;
typedef __attribute__((ext_vector_type(4))) float f32x4;

static __device__ __forceinline__ unsigned short f2bf(float x) {
  __hip_bfloat16 h = __float2bfloat16(x);
  return *reinterpret_cast<unsigned short*>(&h);
}
static __device__ __forceinline__ float bf2f(unsigned short u) {
  return __uint_as_float(((unsigned int)u) << 16);
}

// blocks 0..31: per-batch valid count. block 32: zero S1,S2,PH.
__global__ __launch_bounds__(256) void pre_kernel(const int* __restrict__ mask,
                                                  float* __restrict__ ws) {
  int blk = blockIdx.x, t = threadIdx.x;
  if (blk < Bn) {
    __shared__ int red[256];
    int s = 0;
#pragma unroll
    for (int i = 0; i < 8; i++) s += mask[blk * Ln + i * 256 + t];
    red[t] = s;
    __syncthreads();
    for (int off = 128; off > 0; off >>= 1) {
      if (t < off) red[t] += red[t + off];
      __syncthreads();
    }
    if (t == 0) ws[OFF_CNT + blk] = (float)red[0];
  } else {
#pragma unroll
    for (int i = 0; i < 4; i++) ws[OFF_S1 + i * 256 + t] = 0.f;
#pragma unroll
    for (int i = 0; i < 64; i++) ws[OFF_PH + i * 256 + t] = 0.f;
  }
}

// W1 [768][512] fp32 -> W1t [512][768] bf16
__global__ __launch_bounds__(256) void transpose_w1(
    const float* __restrict__ W1, unsigned short* __restrict__ W1t) {
  __shared__ float tile[32][33];
  int kx = blockIdx.x * 32;
  int nx = blockIdx.y * 32;
  int tx = threadIdx.x & 31, ty = threadIdx.x >> 5;
#pragma unroll
  for (int i = 0; i < 32; i += 8)
    tile[ty + i][tx] = W1[(size_t)(kx + ty + i) * Hn + nx + tx];
  __syncthreads();
#pragma unroll
  for (int i = 0; i < 32; i += 8)
    W1t[(size_t)(nx + ty + i) * Dn + kx + tx] = f2bf(tile[tx][ty + i]);
}

// GEMM1 v6: direct-from-global MFMA. NO LDS staging, NO barriers in K-loop.
// Rationale (r0/r1/r5 ledger): three different LDS-staged schedules all land
// 147-152 us with no pipe >23% busy -- the invariant is the barrier-gated
// staging structure. Shape: N=512,K=768 -> B (768 KB bf16) is L2-resident;
// A streamed once (no reuse) => staging is pure overhead (guide mistake #7).
// Block = 256 thr = 4 waves; wave owns 64x64 (rows by2*64, cols bx*256+w*64).
// A frags: 2x dwordx4 fp32 per mt (16 rows x 128B-line pairs); B frags:
// 1x dwordx4 bf16 per nt from L2/L1. K fully unrolled: offsets fold to
// immediates; compiler free to pipeline across K (no barriers to drain).
// A-panel re-read by 8 col-waves -> L1/L2 dedup (16KB subpanels).
// Hout layout (64-row chunks): chunk=by2 (0..1023), octant wc=bx*4+w:
//   by2*32768 + wc*4096 + (mt*4+nt)*256 + lane*4 + r ; row=mt*16+quad*4+r,
//   col=bx*256+w*64+nt*16+l15.
__global__ __launch_bounds__(256, 2) void gemm1_direct(
    const float* __restrict__ A, const unsigned short* __restrict__ W1t,
    const float* __restrict__ b1, const int* __restrict__ mask,
    unsigned short* __restrict__ Hout,
    float* __restrict__ gsum, float* __restrict__ gsq)
{
  __shared__ float csum[256];
  __shared__ float csq[256];

  const int t = threadIdx.x;
  const int bx = blockIdx.x;         // 0..1  (N half)
  const int by2 = blockIdx.y;        // 0..1023 (64-row chunk)
  const int w = t >> 6;              // 0..3
  const int lane = t & 63;
  const int l15 = lane & 15;
  const int quad = lane >> 4;

  const int row0 = by2 * 64;
  const int col0 = bx * 256 + w * 64;

  // per-lane fragment base pointers (k-offset quad*8 folded in)
  const float* Ap0 = A + (size_t)(row0 +  0 + l15) * Dn + quad * 8;
  const float* Ap1 = A + (size_t)(row0 + 16 + l15) * Dn + quad * 8;
  const float* Ap2 = A + (size_t)(row0 + 32 + l15) * Dn + quad * 8;
  const float* Ap3 = A + (size_t)(row0 + 48 + l15) * Dn + quad * 8;
  const unsigned short* Bp0 = W1t + (size_t)(col0 +  0 + l15) * Dn + quad * 8;
  const unsigned short* Bp1 = W1t + (size_t)(col0 + 16 + l15) * Dn + quad * 8;
  const unsigned short* Bp2 = W1t + (size_t)(col0 + 32 + l15) * Dn + quad * 8;
  const unsigned short* Bp3 = W1t + (size_t)(col0 + 48 + l15) * Dn + quad * 8;

  f32x4 acc[4][4];
#pragma unroll
  for (int i = 0; i < 4; i++)
#pragma unroll
    for (int j = 0; j < 4; j++) acc[i][j] = (f32x4){0.f, 0.f, 0.f, 0.f};

#define CVT8(AF, LO, HI) do { \
  AF[0] = (short)f2bf((LO).x); AF[1] = (short)f2bf((LO).y); \
  AF[2] = (short)f2bf((LO).z); AF[3] = (short)f2bf((LO).w); \
  AF[4] = (short)f2bf((HI).x); AF[5] = (short)f2bf((HI).y); \
  AF[6] = (short)f2bf((HI).z); AF[7] = (short)f2bf((HI).w); \
} while (0)

#pragma unroll
  for (int k0 = 0; k0 < Dn; k0 += 32) {
    bf16x8 bf0 = *(const bf16x8*)(Bp0 + k0);
    bf16x8 bf1 = *(const bf16x8*)(Bp1 + k0);
    bf16x8 bf2 = *(const bf16x8*)(Bp2 + k0);
    bf16x8 bf3 = *(const bf16x8*)(Bp3 + k0);

    float4 a0l = *(const float4*)(Ap0 + k0);
    float4 a0h = *(const float4*)(Ap0 + k0 + 4);
    float4 a1l = *(const float4*)(Ap1 + k0);
    float4 a1h = *(const float4*)(Ap1 + k0 + 4);
    float4 a2l = *(const float4*)(Ap2 + k0);
    float4 a2h = *(const float4*)(Ap2 + k0 + 4);
    float4 a3l = *(const float4*)(Ap3 + k0);
    float4 a3h = *(const float4*)(Ap3 + k0 + 4);

    bf16x8 af0, af1, af2, af3;
    CVT8(af0, a0l, a0h);
    CVT8(af1, a1l, a1h);
    CVT8(af2, a2l, a2h);
    CVT8(af3, a3l, a3h);

    acc[0][0] = __builtin_amdgcn_mfma_f32_16x16x32_bf16(af0, bf0, acc[0][0], 0, 0, 0);
    acc[0][1] = __builtin_amdgcn_mfma_f32_16x16x32_bf16(af0, bf1, acc[0][1], 0, 0, 0);
    acc[0][2] = __builtin_amdgcn_mfma_f32_16x16x32_bf16(af0, bf2, acc[0][2], 0, 0, 0);
    acc[0][3] = __builtin_amdgcn_mfma_f32_16x16x32_bf16(af0, bf3, acc[0][3], 0, 0, 0);
    acc[1][0] = __builtin_amdgcn_mfma_f32_16x16x32_bf16(af1, bf0, acc[1][0], 0, 0, 0);
    acc[1][1] = __builtin_amdgcn_mfma_f32_16x16x32_bf16(af1, bf1, acc[1][1], 0, 0, 0);
    acc[1][2] = __builtin_amdgcn_mfma_f32_16x16x32_bf16(af1, bf2, acc[1][2], 0, 0, 0);
    acc[1][3] = __builtin_amdgcn_mfma_f32_16x16x32_bf16(af1, bf3, acc[1][3], 0, 0, 0);
    acc[2][0] = __builtin_amdgcn_mfma_f32_16x16x32_bf16(af2, bf0, acc[2][0], 0, 0, 0);
    acc[2][1] = __builtin_amdgcn_mfma_f32_16x16x32_bf16(af2, bf1, acc[2][1], 0, 0, 0);
    acc[2][2] = __builtin_amdgcn_mfma_f32_16x16x32_bf16(af2, bf2, acc[2][2], 0, 0, 0);
    acc[2][3] = __builtin_amdgcn_mfma_f32_16x16x32_bf16(af2, bf3, acc[2][3], 0, 0, 0);
    acc[3][0] = __builtin_amdgcn_mfma_f32_16x16x32_bf16(af3, bf0, acc[3][0], 0, 0, 0);
    acc[3][1] = __builtin_amdgcn_mfma_f32_16x16x32_bf16(af3, bf1, acc[3][1], 0, 0, 0);
    acc[3][2] = __builtin_amdgcn_mfma_f32_16x16x32_bf16(af3, bf2, acc[3][2], 0, 0, 0);
    acc[3][3] = __builtin_amdgcn_mfma_f32_16x16x32_bf16(af3, bf3, acc[3][3], 0, 0, 0);
  }
#undef CVT8

  // ---- epilogue: bias, masked stats, coalesced tiled bf16 store ----
  csum[t] = 0.f;
  csq[t] = 0.f;
  __syncthreads();

  float mk[4][4];
#pragma unroll
  for (int mt = 0; mt < 4; mt++) {
    int4 mv = *(const int4*)(mask + row0 + mt * 16 + quad * 4);
    mk[mt][0] = (float)mv.x; mk[mt][1] = (float)mv.y;
    mk[mt][2] = (float)mv.z; mk[mt][3] = (float)mv.w;
  }

  const size_t cbase = (size_t)by2 * 32768 + (size_t)(bx * 4 + w) * 4096;
#pragma unroll
  for (int nt = 0; nt < 4; nt++) {
    const int nl = w * 64 + nt * 16 + l15;          // channel within N-half
    const float bias = b1[bx * 256 + nl];
    float ps = 0.f, pq = 0.f;
#pragma unroll
    for (int mt = 0; mt < 4; mt++) {
      ushort4 st;
      float v0 = acc[mt][nt][0] + bias;
      float v1 = acc[mt][nt][1] + bias;
      float v2 = acc[mt][nt][2] + bias;
      float v3 = acc[mt][nt][3] + bias;
      ps += v0 * mk[mt][0] + v1 * mk[mt][1] + v2 * mk[mt][2] + v3 * mk[mt][3];
      pq += v0 * v0 * mk[mt][0] + v1 * v1 * mk[mt][1] +
            v2 * v2 * mk[mt][2] + v3 * v3 * mk[mt][3];
      st.x = f2bf(v0); st.y = f2bf(v1); st.z = f2bf(v2); st.w = f2bf(v3);
      *(ushort4*)&Hout[cbase + (size_t)(mt * 4 + nt) * 256 + lane * 4] = st;
    }
    atomicAdd(&csum[nl], ps);
    atomicAdd(&csq[nl], pq);
  }

  __syncthreads();
  atomicAdd(&gsum[bx * 256 + t], csum[t]);
  atomicAdd(&gsq[bx * 256 + t], csq[t]);
}

// BN(finalize fused) + ReLU + masked pool over the 64-row-chunk Hout layout.
// 1024 chunks, 512 thr; thread t owns channel t.
__global__ __launch_bounds__(512) void bnpool_kernel(
    const unsigned short* __restrict__ Hbuf, const int* __restrict__ mask,
    const float* __restrict__ ws, const float* __restrict__ gamma,
    const float* __restrict__ beta, float* __restrict__ PH)
{
  __shared__ float mkf[64];
  __shared__ float redc[32];
  const int t = threadIdx.x;
  const int chunk = blockIdx.x;        // 0..1023 (64 rows each)
  const int b = chunk >> 5;            // 32 chunks per batch
  if (t < 32) redc[t] = ws[OFF_CNT + t];
  if (t < 64) mkf[t] = (float)mask[chunk * 64 + t];
  __syncthreads();

  float nv = 0.f;
#pragma unroll
  for (int i = 0; i < 32; i++) nv += redc[i];
  nv = fmaxf(nv, 1.f);
  const float inv = 1.f / nv;
  const int c = t;
  const float m = ws[OFF_S1 + c] * inv;
  const float var = ws[OFF_S2 + c] * inv - m * m;
  const float istd = rsqrtf(fmaxf(var, 0.f) + EPSC);
  const float scv = istd * gamma[c];
  const float shv = beta[c] - m * scv;

  const int wc = t >> 6, nt = (t >> 4) & 3, l15 = t & 15;
  const unsigned short* base =
      Hbuf + (size_t)chunk * 32768 + (size_t)wc * 4096 + nt * 256 + l15 * 4;
  float acc = 0.f;
#pragma unroll
  for (int mt = 0; mt < 4; mt++)
#pragma unroll
    for (int q = 0; q < 4; q++) {
      ushort4 hv = *(const ushort4*)(base + mt * 1024 + q * 64);
      const float* mv = &mkf[mt * 16 + q * 4];
      acc += fmaxf(fmaf(bf2f(hv.x), scv, shv), 0.f) * mv[0]
           + fmaxf(fmaf(bf2f(hv.y), scv, shv), 0.f) * mv[1]
           + fmaxf(fmaf(bf2f(hv.z), scv, shv), 0.f) * mv[2]
           + fmaxf(fmaf(bf2f(hv.w), scv, shv), 0.f) * mv[3];
    }
  atomicAdd(&PH[b * Hn + c], acc);
}

// out[b][c] = (PH[b]/max(cnt,1)) @ W2[:,c] + b2[c]*(cnt/max(cnt,1))
__global__ __launch_bounds__(128) void final_kernel(
    const float* __restrict__ pooledh, const float* __restrict__ cnt,
    const float* __restrict__ W2, const float* __restrict__ b2,
    float* __restrict__ out)
{
  __shared__ float pr[Hn];
  int b = blockIdx.x >> 2;
  int cc = blockIdx.x & 3;
  int t = threadIdx.x;
  float nb = cnt[b];
  float inv = 1.f / fmaxf(nb, 1.f);
#pragma unroll
  for (int i = 0; i < 4; i++)
    pr[t + i * 128] = pooledh[b * Hn + t + i * 128] * inv;
  __syncthreads();
  int c = cc * 128 + t;
  float a0 = 0.f, a1 = 0.f, a2 = 0.f, a3 = 0.f;
  for (int i = 0; i < Hn; i += 4) {
    a0 = fmaf(pr[i],     W2[(size_t)i * Hn + c],       a0);
    a1 = fmaf(pr[i + 1], W2[(size_t)(i + 1) * Hn + c], a1);
    a2 = fmaf(pr[i + 2], W2[(size_t)(i + 2) * Hn + c], a2);
    a3 = fmaf(pr[i + 3], W2[(size_t)(i + 3) * Hn + c], a3);
  }
  out[b * Hn + c] = (a0 + a1) + (a2 + a3) + b2[c] * (nb * inv);
}

extern "C" void kernel_launch(void* const* d_in, const int* in_sizes, int n_in,
                              void* d_out, int out_size, void* d_ws, size_t ws_size,
                              hipStream_t stream) {
  const float* hidden = (const float*)d_in[0];
  const int*   mask   = (const int*)d_in[1];
  const float* W1     = (const float*)d_in[2];
  const float* b1     = (const float*)d_in[3];
  const float* gamma  = (const float*)d_in[4];
  const float* beta   = (const float*)d_in[5];
  const float* W2     = (const float*)d_in[6];
  const float* b2     = (const float*)d_in[7];
  float* out = (float*)d_out;
  float* ws  = (float*)d_ws;
  unsigned short* W1t  = (unsigned short*)((char*)d_ws + OFF_W1T_BYTES);
  unsigned short* Hbuf = (unsigned short*)((char*)d_ws + OFF_H_BYTES);

  pre_kernel<<<Bn + 1, 256, 0, stream>>>(mask, ws);
  transpose_w1<<<dim3(Dn / 32, Hn / 32), 256, 0, stream>>>(W1, W1t);
  gemm1_direct<<<dim3(2, Mn / 64), 256, 0, stream>>>(
      hidden, W1t, b1, mask, Hbuf, ws + OFF_S1, ws + OFF_S2);
  bnpool_kernel<<<Mn / 64, 512, 0, stream>>>(
      Hbuf, mask, ws, gamma, beta, ws + OFF_PH);
  final_kernel<<<Bn * 4, 128, 0, stream>>>(ws + OFF_PH, ws + OFF_CNT, W2, b2, out);
}

// Round 7
// 406.275 us; speedup vs baseline: 1.4066x; 1.4066x over previous
//
#include <hip/hip_runtime.h>
#include <hip/hip_bf16.h>

#define Bn 32
#define Ln 2048
#define Dn 768
#define Hn 512
#define Mn (Bn*Ln)
#define EPSC 1e-5f

// ws float-offset layout (first 128 KB), then byte regions
#define OFF_S1   0        // [512] masked sum(h)
#define OFF_S2   512      // [512] masked sum(h^2)
#define OFF_CNT  2048     // [32] per-batch counts
#define OFF_PH   2304     // [32*512] pooled relu(BN(h)) sums (atomic)
#define OFF_W1T_BYTES  131072   // bf16 W1^T [512][768] = 786 KB
#define OFF_H_BYTES    1048576  // tiled bf16 h buffer, 64 MB

#define BM 128
#define BN2 256
#define BK 64
#define KT_N 12        // 768/64 K-tiles

typedef __attribute__((ext_vector_type(8))) short bf16x8;
typedef __attribute__((ext_vector_type(4))) float f32x4;

static __device__ __forceinline__ unsigned short f2bf(float x) {
  __hip_bfloat16 h = __float2bfloat16(x);
  return *reinterpret_cast<unsigned short*>(&h);
}
static __device__ __forceinline__ float bf2f(unsigned short u) {
  return __uint_as_float(((unsigned int)u) << 16);
}

// prep: blocks 0..31 per-batch counts; block 32 zeros S1,S2,PH;
// blocks 33..416 transpose W1 (768x512 fp32 -> 512x768 bf16).
// (verified passing in round 3)
__global__ __launch_bounds__(256) void prep_kernel(
    const int* __restrict__ mask, const float* __restrict__ W1,
    unsigned short* __restrict__ W1t, float* __restrict__ ws) {
  int blk = blockIdx.x, t = threadIdx.x;
  if (blk < Bn) {
    __shared__ int red[256];
    int s = 0;
#pragma unroll
    for (int i = 0; i < 8; i++) s += mask[blk * Ln + i * 256 + t];
    red[t] = s;
    __syncthreads();
    for (int off = 128; off > 0; off >>= 1) {
      if (t < off) red[t] += red[t + off];
      __syncthreads();
    }
    if (t == 0) ws[OFF_CNT + blk] = (float)red[0];
  } else if (blk == Bn) {
#pragma unroll
    for (int i = 0; i < 4; i++) ws[OFF_S1 + i * 256 + t] = 0.f;
#pragma unroll
    for (int i = 0; i < 64; i++) ws[OFF_PH + i * 256 + t] = 0.f;
  } else {
    __shared__ float tile[32][33];
    int tb = blk - (Bn + 1);          // 0..383
    int kx = (tb % 24) * 32;          // Dn/32 = 24
    int nx = (tb / 24) * 32;          // Hn/32 = 16
    int tx = t & 31, ty = t >> 5;
#pragma unroll
    for (int i = 0; i < 32; i += 8)
      tile[ty + i][tx] = W1[(size_t)(kx + ty + i) * Hn + nx + tx];
    __syncthreads();
#pragma unroll
    for (int i = 0; i < 32; i += 8)
      W1t[(size_t)(nx + ty + i) * Dn + kx + tx] = f2bf(tile[tx][ty + i]);
  }
}

// GEMM1 v7: ring-3 LDS + depth-2 prefetch, counted vmcnt(8) boundaries.
//  - As3/Bs3: 3 K-tile slots each (144 KB). Compute kt from slot kt%3;
//    stage kt+2 into slot (kt+2)%3 (= slot of kt-1, freed at kt-1's end
//    barrier). Writers never touch a slot in use -> no drain coupling.
//  - A: greg(kt+2) issued at kt (2 ping-pong reg sets), cvt+ds_write at
//    kt+1 (distance ~2 phases); B: gload_lds(kt+2) issued at kt.
//  - Boundary wait vmcnt(8): entering kt, FIFO = {B(kt):4, AG(kt+1):4,
//    B(kt+1):4} = 12 -> drain exactly B(kt), keep 8 flying. Never 0
//    mid-loop. WRA auto-waits drain only <= AG(kt+1) (issue order).
//  - 2 phases per kt (s=0/1): {wait, ds_read 8, stage, barrier, lgkm0,
//    setprio1, 16 MFMA, setprio0, barrier}.
// Swizzles, A/B maps, epilogue, Hout layout: r5-verbatim (0-conflict,
// numerically verified). LDS 144 KB -> 1 block/CU.
__global__ __launch_bounds__(512) void gemm1_mfma(
    const float* __restrict__ A, const unsigned short* __restrict__ W1t,
    const float* __restrict__ b1, const int* __restrict__ mask,
    unsigned short* __restrict__ Hout,
    float* __restrict__ gsum, float* __restrict__ gsq)
{
  __shared__ __align__(16) unsigned short As3[3][BM * BK];   // 48 KB
  __shared__ __align__(16) unsigned short Bs3[3][BN2 * BK];  // 96 KB

  const int t = threadIdx.x;
  const int bx = blockIdx.x;   // N: 0..1
  const int by = blockIdx.y;   // M: 0..511
  const int bm0 = by * BM;
  const int bn0 = bx * BN2;

  const int w = t >> 6;
  const int lane = t & 63;
  const int wm0 = (w >> 2) * 64;
  const int wn0 = (w & 3) * 64;
  const int l15 = lane & 15;
  const int quad = lane >> 4;
  const int swz = (l15 & 7) << 4;        // read-side XOR (row&7 == l15&7)
  const int aAr = (wm0 + l15) * 128;     // A read row-base (bytes in slot)
  const int aBr = (wn0 + l15) * 128;     // B read row-base

  // A staging map: thread covers 16 consecutive fp32 of its row
  const int am = t >> 2;                 // 0..127
  const int akc = (t & 3) * 16;          // fp32 col 0/16/32/48
  const float* Ap = A + (size_t)(bm0 + am) * Dn + akc;
  const int ab0 = am * 128 + ((akc * 2) ^ ((am & 7) << 4));
  const int ab1 = am * 128 + ((akc * 2 + 16) ^ ((am & 7) << 4));

  // B staging per-thread constants: phys p -> logical q (involution)
  const int p0 = ((w * 2 + 0) << 10) + (lane << 4);
  const int p1 = ((w * 2 + 1) << 10) + (lane << 4);
  const int q0 = p0 ^ (((p0 >> 7) & 7) << 4);
  const int q1 = p1 ^ (((p1 >> 7) & 7) << 4);
  const char* bsrc00 = (const char*)(W1t + (size_t)(bn0 +   0 + (q0 >> 7)) * Dn) + (q0 & 127);
  const char* bsrc01 = (const char*)(W1t + (size_t)(bn0 +   0 + (q1 >> 7)) * Dn) + (q1 & 127);
  const char* bsrc10 = (const char*)(W1t + (size_t)(bn0 + 128 + (q0 >> 7)) * Dn) + (q0 & 127);
  const char* bsrc11 = (const char*)(W1t + (size_t)(bn0 + 128 + (q1 >> 7)) * Dn) + (q1 & 127);
  const int bd0 = (w * 2 + 0) << 10;     // LDS dest (wave-uniform part)
  const int bd1 = (w * 2 + 1) << 10;

  f32x4 acc[4][4];
#pragma unroll
  for (int i = 0; i < 4; i++)
#pragma unroll
    for (int j = 0; j < 4; j++) acc[i][j] = (f32x4){0.f, 0.f, 0.f, 0.f};

  float4 rAe[4], rAo[4];                 // depth-2 A prefetch sets
  bf16x8 af0, af1, af2, af3, bf0, bf1, bf2, bf3;

#define WAITV(N) do { asm volatile("s_waitcnt vmcnt(" #N ")" ::: "memory"); \
                      __builtin_amdgcn_sched_barrier(0); } while (0)
#define LG0()    do { asm volatile("s_waitcnt lgkmcnt(0)" ::: "memory"); \
                      __builtin_amdgcn_sched_barrier(0); } while (0)

  // stage B K-tile KT (2 half-tiles worth issued together = 4 ops: here
  // split by H; each call = 2 gload_lds)
#define SBH(KT, H) do { \
  __builtin_amdgcn_global_load_lds( \
      (const __attribute__((address_space(1))) void*)(((H) ? bsrc10 : bsrc00) + (KT) * 128), \
      (__attribute__((address_space(3))) void*)((char*)&Bs3[(KT) % 3][0] + (H) * 16384 + bd0), \
      16, 0, 0); \
  __builtin_amdgcn_global_load_lds( \
      (const __attribute__((address_space(1))) void*)(((H) ? bsrc11 : bsrc01) + (KT) * 128), \
      (__attribute__((address_space(3))) void*)((char*)&Bs3[(KT) % 3][0] + (H) * 16384 + bd1), \
      16, 0, 0); \
} while (0)

#define AG(KT2, R) do { \
  R[0] = *(const float4*)(Ap + (KT2) * BK); \
  R[1] = *(const float4*)(Ap + (KT2) * BK + 4); \
  R[2] = *(const float4*)(Ap + (KT2) * BK + 8); \
  R[3] = *(const float4*)(Ap + (KT2) * BK + 12); \
} while (0)

#define WRA(R, KTD) do { \
  uint4 w0, w1; \
  w0.x = (unsigned)f2bf(R[0].x) | ((unsigned)f2bf(R[0].y) << 16); \
  w0.y = (unsigned)f2bf(R[0].z) | ((unsigned)f2bf(R[0].w) << 16); \
  w0.z = (unsigned)f2bf(R[1].x) | ((unsigned)f2bf(R[1].y) << 16); \
  w0.w = (unsigned)f2bf(R[1].z) | ((unsigned)f2bf(R[1].w) << 16); \
  w1.x = (unsigned)f2bf(R[2].x) | ((unsigned)f2bf(R[2].y) << 16); \
  w1.y = (unsigned)f2bf(R[2].z) | ((unsigned)f2bf(R[2].w) << 16); \
  w1.z = (unsigned)f2bf(R[3].x) | ((unsigned)f2bf(R[3].y) << 16); \
  w1.w = (unsigned)f2bf(R[3].z) | ((unsigned)f2bf(R[3].w) << 16); \
  *(uint4*)((char*)&As3[(KTD) % 3][0] + ab0) = w0; \
  *(uint4*)((char*)&As3[(KTD) % 3][0] + ab1) = w1; \
} while (0)

#define DSR(KT, S) do { \
  const char* Ab = (const char*)&As3[(KT) % 3][0]; \
  const char* Bb = (const char*)&Bs3[(KT) % 3][0]; \
  const int co = ((S) * 64 + quad * 16) ^ swz; \
  af0 = *(const bf16x8*)(Ab + aAr +    0 + co); \
  af1 = *(const bf16x8*)(Ab + aAr + 2048 + co); \
  af2 = *(const bf16x8*)(Ab + aAr + 4096 + co); \
  af3 = *(const bf16x8*)(Ab + aAr + 6144 + co); \
  bf0 = *(const bf16x8*)(Bb + aBr +    0 + co); \
  bf1 = *(const bf16x8*)(Bb + aBr + 2048 + co); \
  bf2 = *(const bf16x8*)(Bb + aBr + 4096 + co); \
  bf3 = *(const bf16x8*)(Bb + aBr + 6144 + co); \
} while (0)

#define MFMAS() do { \
  acc[0][0] = __builtin_amdgcn_mfma_f32_16x16x32_bf16(af0, bf0, acc[0][0], 0, 0, 0); \
  acc[0][1] = __builtin_amdgcn_mfma_f32_16x16x32_bf16(af0, bf1, acc[0][1], 0, 0, 0); \
  acc[0][2] = __builtin_amdgcn_mfma_f32_16x16x32_bf16(af0, bf2, acc[0][2], 0, 0, 0); \
  acc[0][3] = __builtin_amdgcn_mfma_f32_16x16x32_bf16(af0, bf3, acc[0][3], 0, 0, 0); \
  acc[1][0] = __builtin_amdgcn_mfma_f32_16x16x32_bf16(af1, bf0, acc[1][0], 0, 0, 0); \
  acc[1][1] = __builtin_amdgcn_mfma_f32_16x16x32_bf16(af1, bf1, acc[1][1], 0, 0, 0); \
  acc[1][2] = __builtin_amdgcn_mfma_f32_16x16x32_bf16(af1, bf2, acc[1][2], 0, 0, 0); \
  acc[1][3] = __builtin_amdgcn_mfma_f32_16x16x32_bf16(af1, bf3, acc[1][3], 0, 0, 0); \
  acc[2][0] = __builtin_amdgcn_mfma_f32_16x16x32_bf16(af2, bf0, acc[2][0], 0, 0, 0); \
  acc[2][1] = __builtin_amdgcn_mfma_f32_16x16x32_bf16(af2, bf1, acc[2][1], 0, 0, 0); \
  acc[2][2] = __builtin_amdgcn_mfma_f32_16x16x32_bf16(af2, bf2, acc[2][2], 0, 0, 0); \
  acc[2][3] = __builtin_amdgcn_mfma_f32_16x16x32_bf16(af2, bf3, acc[2][3], 0, 0, 0); \
  acc[3][0] = __builtin_amdgcn_mfma_f32_16x16x32_bf16(af3, bf0, acc[3][0], 0, 0, 0); \
  acc[3][1] = __builtin_amdgcn_mfma_f32_16x16x32_bf16(af3, bf1, acc[3][1], 0, 0, 0); \
  acc[3][2] = __builtin_amdgcn_mfma_f32_16x16x32_bf16(af3, bf2, acc[3][2], 0, 0, 0); \
  acc[3][3] = __builtin_amdgcn_mfma_f32_16x16x32_bf16(af3, bf3, acc[3][3], 0, 0, 0); \
} while (0)

  // K-tile block: RAG receives AG(kt+2); RWR holds kt+1 data (written here).
#define KTB(KT, RAG, RWR) do { \
  /* phase 0 (s=0) */ \
  if ((KT) < 11) { WAITV(8); } else { WAITV(0); } \
  DSR(KT, 0); \
  if ((KT) <= 9) AG((KT) + 2, RAG); \
  if ((KT) >= 1 && (KT) <= 10) WRA(RWR, (KT) + 1); \
  if ((KT) <= 9) SBH((KT) + 2, 0); \
  __builtin_amdgcn_s_barrier(); \
  LG0(); \
  __builtin_amdgcn_s_setprio(1); MFMAS(); __builtin_amdgcn_s_setprio(0); \
  __builtin_amdgcn_s_barrier(); \
  /* phase 1 (s=1) */ \
  DSR(KT, 1); \
  if ((KT) <= 9) SBH((KT) + 2, 1); \
  __builtin_amdgcn_s_barrier(); \
  LG0(); \
  __builtin_amdgcn_s_setprio(1); MFMAS(); __builtin_amdgcn_s_setprio(0); \
  __builtin_amdgcn_s_barrier(); \
} while (0)

  // ---- prologue: stage kt0, kt1 fully; leave B(1) in flight ----
  AG(0, rAe);
  WRA(rAe, 0);          // auto-waits AG(0)
  AG(1, rAo);
  WRA(rAo, 1);          // auto-waits AG(1)
  SBH(0, 0); SBH(0, 1); SBH(1, 0); SBH(1, 1);
  WAITV(4);             // drain B(0); B(1):4 stays in flight
  LG0();
  __builtin_amdgcn_s_barrier();

  // ---- main loop: 12 K-tiles, fully unrolled ----
#pragma unroll
  for (int k2 = 0; k2 < 6; ++k2) {
    KTB(k2 * 2,     rAe, rAo);    // even kt: AG->rAe, write rAo (kt+1 data)
    KTB(k2 * 2 + 1, rAo, rAe);    // odd  kt: AG->rAo, write rAe
  }

#undef KTB
#undef MFMAS
#undef DSR
#undef WRA
#undef AG
#undef SBH
#undef LG0
#undef WAITV

  // ---- epilogue: bias, masked stats, coalesced tiled bf16 store ----
  float* csum = (float*)&As3[0][0];    // [256] (LDS dead after k-loop)
  float* csq  = csum + BN2;            // [256]
  if (t < BN2) { csum[t] = 0.f; csq[t] = 0.f; }
  __syncthreads();

  float mk[4][4];
#pragma unroll
  for (int mt = 0; mt < 4; mt++) {
    int4 mv = *(const int4*)(mask + bm0 + wm0 + mt * 16 + quad * 4);
    mk[mt][0] = (float)mv.x; mk[mt][1] = (float)mv.y;
    mk[mt][2] = (float)mv.z; mk[mt][3] = (float)mv.w;
  }

  const size_t cbase = ((size_t)(by * 2 + bx)) * 32768 + (size_t)w * 4096;
#pragma unroll
  for (int nt = 0; nt < 4; nt++) {
    const int nl = wn0 + nt * 16 + l15;
    const float bias = b1[bn0 + nl];
    float ps = 0.f, pq = 0.f;
#pragma unroll
    for (int mt = 0; mt < 4; mt++) {
      ushort4 st;
      float v0 = acc[mt][nt][0] + bias;
      float v1 = acc[mt][nt][1] + bias;
      float v2 = acc[mt][nt][2] + bias;
      float v3 = acc[mt][nt][3] + bias;
      ps += v0 * mk[mt][0] + v1 * mk[mt][1] + v2 * mk[mt][2] + v3 * mk[mt][3];
      pq += v0 * v0 * mk[mt][0] + v1 * v1 * mk[mt][1] +
            v2 * v2 * mk[mt][2] + v3 * v3 * mk[mt][3];
      st.x = f2bf(v0); st.y = f2bf(v1); st.z = f2bf(v2); st.w = f2bf(v3);
      *(ushort4*)&Hout[cbase + (size_t)(mt * 4 + nt) * 256 + lane * 4] = st;
    }
    atomicAdd(&csum[nl], ps);
    atomicAdd(&csq[nl], pq);
  }

  __syncthreads();
  if (t < BN2) {
    atomicAdd(&gsum[bn0 + t], csum[t]);
    atomicAdd(&gsq[bn0 + t], csq[t]);
  }
}

// BN(finalize fused) + ReLU + masked pool over the tiled Hout layout.
__global__ __launch_bounds__(256) void bnpool_kernel(
    const unsigned short* __restrict__ Hbuf, const int* __restrict__ mask,
    const float* __restrict__ ws, const float* __restrict__ gamma,
    const float* __restrict__ beta, float* __restrict__ PH)
{
  __shared__ float mkf[BM];
  __shared__ float redc[32];
  const int t = threadIdx.x;
  const int chunk = blockIdx.x;        // 0..1023
  const int by = chunk >> 1, bx = chunk & 1;
  const int b = chunk >> 5;            // 32 chunks per batch
  if (t < 32) redc[t] = ws[OFF_CNT + t];
  if (t < BM) mkf[t] = (float)mask[by * BM + t];
  __syncthreads();

  float nv = 0.f;
#pragma unroll
  for (int i = 0; i < 32; i++) nv += redc[i];
  nv = fmaxf(nv, 1.f);
  const float inv = 1.f / nv;
  const int c = bx * BN2 + t;
  const float m = ws[OFF_S1 + c] * inv;
  const float var = ws[OFF_S2 + c] * inv - m * m;
  const float istd = rsqrtf(fmaxf(var, 0.f) + EPSC);
  const float scv = istd * gamma[c];
  const float shv = beta[c] - m * scv;

  const int w3 = t >> 6, nt = (t >> 4) & 3, l15 = t & 15;
  float acc = 0.f;
#pragma unroll
  for (int h = 0; h < 2; h++) {
    const int w = w3 + h * 4;          // same wn0 group, wm half h
    const int wm0 = h * 64;
    const unsigned short* base =
        Hbuf + (size_t)chunk * 32768 + (size_t)w * 4096 + nt * 256 + l15 * 4;
#pragma unroll
    for (int mt = 0; mt < 4; mt++)
#pragma unroll
      for (int q = 0; q < 4; q++) {
        ushort4 hv = *(const ushort4*)(base + mt * 1024 + q * 64);
        const float* mv = &mkf[wm0 + mt * 16 + q * 4];
        acc += fmaxf(fmaf(bf2f(hv.x), scv, shv), 0.f) * mv[0]
             + fmaxf(fmaf(bf2f(hv.y), scv, shv), 0.f) * mv[1]
             + fmaxf(fmaf(bf2f(hv.z), scv, shv), 0.f) * mv[2]
             + fmaxf(fmaf(bf2f(hv.w), scv, shv), 0.f) * mv[3];
      }
  }
  atomicAdd(&PH[b * Hn + c], acc);
}

// out[b][c] = (PH[b]/max(cnt,1)) @ W2[:,c] + b2[c]*(cnt/max(cnt,1))
__global__ __launch_bounds__(128) void final_kernel(
    const float* __restrict__ pooledh, const float* __restrict__ cnt,
    const float* __restrict__ W2, const float* __restrict__ b2,
    float* __restrict__ out)
{
  __shared__ float pr[Hn];
  int b = blockIdx.x >> 2;
  int cc = blockIdx.x & 3;
  int t = threadIdx.x;
  float nb = cnt[b];
  float inv = 1.f / fmaxf(nb, 1.f);
#pragma unroll
  for (int i = 0; i < 4; i++)
    pr[t + i * 128] = pooledh[b * Hn + t + i * 128] * inv;
  __syncthreads();
  int c = cc * 128 + t;
  float a0 = 0.f, a1 = 0.f, a2 = 0.f, a3 = 0.f;
  for (int i = 0; i < Hn; i += 4) {
    a0 = fmaf(pr[i],     W2[(size_t)i * Hn + c],       a0);
    a1 = fmaf(pr[i + 1], W2[(size_t)(i + 1) * Hn + c], a1);
    a2 = fmaf(pr[i + 2], W2[(size_t)(i + 2) * Hn + c], a2);
    a3 = fmaf(pr[i + 3], W2[(size_t)(i + 3) * Hn + c], a3);
  }
  out[b * Hn + c] = (a0 + a1) + (a2 + a3) + b2[c] * (nb * inv);
}

extern "C" void kernel_launch(void* const* d_in, const int* in_sizes, int n_in,
                              void* d_out, int out_size, void* d_ws, size_t ws_size,
                              hipStream_t stream) {
  const float* hidden = (const float*)d_in[0];
  const int*   mask   = (const int*)d_in[1];
  const float* W1     = (const float*)d_in[2];
  const float* b1     = (const float*)d_in[3];
  const float* gamma  = (const float*)d_in[4];
  const float* beta   = (const float*)d_in[5];
  const float* W2     = (const float*)d_in[6];
  const float* b2     = (const float*)d_in[7];
  float* out = (float*)d_out;
  float* ws  = (float*)d_ws;
  unsigned short* W1t  = (unsigned short*)((char*)d_ws + OFF_W1T_BYTES);
  unsigned short* Hbuf = (unsigned short*)((char*)d_ws + OFF_H_BYTES);

  prep_kernel<<<Bn + 1 + (Dn / 32) * (Hn / 32), 256, 0, stream>>>(
      mask, W1, W1t, ws);
  gemm1_mfma<<<dim3(Hn / BN2, Mn / BM), 512, 0, stream>>>(
      hidden, W1t, b1, mask, Hbuf, ws + OFF_S1, ws + OFF_S2);
  bnpool_kernel<<<(Mn / BM) * (Hn / BN2), 256, 0, stream>>>(
      Hbuf, mask, ws, gamma, beta, ws + OFF_PH);
  final_kernel<<<Bn * 4, 128, 0, stream>>>(ws + OFF_PH, ws + OFF_CNT, W2, b2, out);
}

// Round 8
// 368.849 us; speedup vs baseline: 1.5493x; 1.1015x over previous
//
#include <hip/hip_runtime.h>
#include <hip/hip_bf16.h>

#define Bn 32
#define Ln 2048
#define Dn 768
#define Hn 512
#define Mn (Bn*Ln)
#define EPSC 1e-5f

// ws float-offset layout (first 128 KB), then byte regions
#define OFF_S1   0        // [512] masked sum(h)
#define OFF_S2   512      // [512] masked sum(h^2)
#define OFF_CNT  2048     // [32] per-batch counts
#define OFF_PH   2304     // [32*512] pooled relu(BN(h)) sums (atomic)
#define OFF_W1T_BYTES  131072   // bf16 W1^T [512][768] = 786 KB
#define OFF_H_BYTES    1048576  // tiled bf16 h buffer, 64 MB

#define BM 128
#define BN2 256
#define BK 64
#define LDK 72   // padded LDS k-stride for A (bf16): r0-verified
#define KT_N (Dn/BK)

typedef __attribute__((ext_vector_type(8))) short bf16x8;
typedef __attribute__((ext_vector_type(4))) float f32x4;

static __device__ __forceinline__ unsigned short f2bf(float x) {
  __hip_bfloat16 h = __float2bfloat16(x);
  return *reinterpret_cast<unsigned short*>(&h);
}
static __device__ __forceinline__ float bf2f(unsigned short u) {
  return __uint_as_float(((unsigned int)u) << 16);
}

// prep: blocks 0..31 per-batch counts; block 32 zeros S1,S2,PH;
// blocks 33..416 transpose W1 (768x512 fp32 -> 512x768 bf16). (r3/r7-verified)
__global__ __launch_bounds__(256) void prep_kernel(
    const int* __restrict__ mask, const float* __restrict__ W1,
    unsigned short* __restrict__ W1t, float* __restrict__ ws) {
  int blk = blockIdx.x, t = threadIdx.x;
  if (blk < Bn) {
    __shared__ int red[256];
    int s = 0;
#pragma unroll
    for (int i = 0; i < 8; i++) s += mask[blk * Ln + i * 256 + t];
    red[t] = s;
    __syncthreads();
    for (int off = 128; off > 0; off >>= 1) {
      if (t < off) red[t] += red[t + off];
      __syncthreads();
    }
    if (t == 0) ws[OFF_CNT + blk] = (float)red[0];
  } else if (blk == Bn) {
#pragma unroll
    for (int i = 0; i < 4; i++) ws[OFF_S1 + i * 256 + t] = 0.f;
#pragma unroll
    for (int i = 0; i < 64; i++) ws[OFF_PH + i * 256 + t] = 0.f;
  } else {
    __shared__ float tile[32][33];
    int tb = blk - (Bn + 1);          // 0..383
    int kx = (tb % 24) * 32;          // Dn/32 = 24
    int nx = (tb / 24) * 32;          // Hn/32 = 16
    int tx = t & 31, ty = t >> 5;
#pragma unroll
    for (int i = 0; i < 32; i += 8)
      tile[ty + i][tx] = W1[(size_t)(kx + ty + i) * Hn + nx + tx];
    __syncthreads();
#pragma unroll
    for (int i = 0; i < 32; i += 8)
      W1t[(size_t)(nx + ty + i) * Dn + kx + tx] = f2bf(tile[tx][ty + i]);
  }
}

// GEMM1 v8: r0's winning schedule (2 __syncthreads/kt full-drain, 2 blocks/CU)
// with EXACTLY ONE change isolated: B staged via global_load_lds (width 16,
// pre-swizzled source; r5-numerically-verified formulas) instead of the VGPR
// round-trip (4 loads + 4 ds_write_b128/thread/kt removed). A path, epilogue,
// Hout layout: r0-verbatim. LDS 52.4 KB; LB(512,4) (r0: VGPR 56, no spill;
// this version has FEWER live regs).
// Hout layout: chunk = by*2+bx; w*4096 + (mt*4+nt)*256 + lane*4 + r
__global__ __launch_bounds__(512, 4) void gemm1_mfma(
    const float* __restrict__ A, const unsigned short* __restrict__ W1t,
    const float* __restrict__ b1, const int* __restrict__ mask,
    unsigned short* __restrict__ Hout,
    float* __restrict__ gsum, float* __restrict__ gsq)
{
  __shared__ unsigned short As[BM * LDK];                  // 18.4 KB padded
  __shared__ __align__(16) unsigned short Bs[BN2 * BK];    // 32 KB swizzled
  __shared__ float csum[BN2];
  __shared__ float csq[BN2];

  const int t = threadIdx.x;
  const int bx = blockIdx.x;   // N: 0..1
  const int by = blockIdx.y;   // M: 0..511
  const int bm0 = by * BM;
  const int bn0 = bx * BN2;

  const int w = t >> 6;
  const int lane = t & 63;
  const int wm0 = (w >> 2) * 64;
  const int wn0 = (w & 3) * 64;
  const int l15 = lane & 15;
  const int quad = lane >> 4;

  // A staging map (r0): thread covers 16 consecutive floats of its row
  const int am = t >> 2;           // 0..127
  const int ak = (t & 3) * 16;     // 0/16/32/48
  const float* Ap = A + (size_t)(bm0 + am) * Dn + ak;

  // B staging (r5-verified): phys LDS byte p holds logical tile byte
  // q = p ^ ((p>>7 & 7)<<4). Per-thread pre-swizzled global sources.
  const int p0 = ((w * 4 + 0) << 10) + (lane << 4);
  const int p1 = ((w * 4 + 1) << 10) + (lane << 4);
  const int p2 = ((w * 4 + 2) << 10) + (lane << 4);
  const int p3 = ((w * 4 + 3) << 10) + (lane << 4);
  const int q0 = p0 ^ (((p0 >> 7) & 7) << 4);
  const int q1 = p1 ^ (((p1 >> 7) & 7) << 4);
  const int q2 = p2 ^ (((p2 >> 7) & 7) << 4);
  const int q3 = p3 ^ (((p3 >> 7) & 7) << 4);
  const char* bsrc0 = (const char*)(W1t + (size_t)(bn0 + (q0 >> 7)) * Dn) + (q0 & 127);
  const char* bsrc1 = (const char*)(W1t + (size_t)(bn0 + (q1 >> 7)) * Dn) + (q1 & 127);
  const char* bsrc2 = (const char*)(W1t + (size_t)(bn0 + (q2 >> 7)) * Dn) + (q2 & 127);
  const char* bsrc3 = (const char*)(W1t + (size_t)(bn0 + (q3 >> 7)) * Dn) + (q3 & 127);

  f32x4 acc[4][4];
#pragma unroll
  for (int i = 0; i < 4; i++)
#pragma unroll
    for (int j = 0; j < 4; j++) acc[i][j] = (f32x4){0.f, 0.f, 0.f, 0.f};

  for (int k0 = 0; k0 < Dn; k0 += BK) {
    // A -> VGPRs (pre-barrier: VGPR dest, no LDS hazard)
    float4 a0 = *(const float4*)(Ap + k0);
    float4 a1 = *(const float4*)(Ap + k0 + 4);
    float4 a2 = *(const float4*)(Ap + k0 + 8);
    float4 a3 = *(const float4*)(Ap + k0 + 12);
    __syncthreads();   // prev kt's LDS reads retired
    // B: 4x global_load_lds dwordx4 (LDS dest wave-uniform + lane*16 by HW)
    __builtin_amdgcn_global_load_lds(
        (const __attribute__((address_space(1))) void*)(bsrc0 + k0 * 2),
        (__attribute__((address_space(3))) void*)((char*)&Bs[0] + ((w * 4 + 0) << 10)),
        16, 0, 0);
    __builtin_amdgcn_global_load_lds(
        (const __attribute__((address_space(1))) void*)(bsrc1 + k0 * 2),
        (__attribute__((address_space(3))) void*)((char*)&Bs[0] + ((w * 4 + 1) << 10)),
        16, 0, 0);
    __builtin_amdgcn_global_load_lds(
        (const __attribute__((address_space(1))) void*)(bsrc2 + k0 * 2),
        (__attribute__((address_space(3))) void*)((char*)&Bs[0] + ((w * 4 + 2) << 10)),
        16, 0, 0);
    __builtin_amdgcn_global_load_lds(
        (const __attribute__((address_space(1))) void*)(bsrc3 + k0 * 2),
        (__attribute__((address_space(3))) void*)((char*)&Bs[0] + ((w * 4 + 3) << 10)),
        16, 0, 0);
    // A: cvt + pack + ds_write (r0-verbatim, padded stride)
    uint4 w0, w1;
    w0.x = (unsigned)f2bf(a0.x) | ((unsigned)f2bf(a0.y) << 16);
    w0.y = (unsigned)f2bf(a0.z) | ((unsigned)f2bf(a0.w) << 16);
    w0.z = (unsigned)f2bf(a1.x) | ((unsigned)f2bf(a1.y) << 16);
    w0.w = (unsigned)f2bf(a1.z) | ((unsigned)f2bf(a1.w) << 16);
    w1.x = (unsigned)f2bf(a2.x) | ((unsigned)f2bf(a2.y) << 16);
    w1.y = (unsigned)f2bf(a2.z) | ((unsigned)f2bf(a2.w) << 16);
    w1.z = (unsigned)f2bf(a3.x) | ((unsigned)f2bf(a3.y) << 16);
    w1.w = (unsigned)f2bf(a3.z) | ((unsigned)f2bf(a3.w) << 16);
    *(uint4*)&As[am * LDK + ak] = w0;
    *(uint4*)&As[am * LDK + ak + 8] = w1;
    __syncthreads();   // implicit vmcnt(0)+lgkm(0): Bs landed, As visible
#pragma unroll
    for (int s = 0; s < 2; s++) {
      bf16x8 af[4], bf[4];
#pragma unroll
      for (int mt = 0; mt < 4; mt++)
        af[mt] = *(const bf16x8*)&As[(wm0 + mt * 16 + l15) * LDK + s * 32 + quad * 8];
#pragma unroll
      for (int nt = 0; nt < 4; nt++) {
        const int rb = wn0 + nt * 16 + l15;
        const int cb = (s * 64 + quad * 16) ^ ((rb & 7) << 4);
        bf[nt] = *(const bf16x8*)((const char*)&Bs[0] + rb * 128 + cb);
      }
#pragma unroll
      for (int mt = 0; mt < 4; mt++)
#pragma unroll
        for (int nt = 0; nt < 4; nt++)
          acc[mt][nt] = __builtin_amdgcn_mfma_f32_16x16x32_bf16(
              af[mt], bf[nt], acc[mt][nt], 0, 0, 0);
    }
  }

  // ---- epilogue: bias, masked stats, coalesced tiled bf16 store (r0) ----
  if (t < BN2) { csum[t] = 0.f; csq[t] = 0.f; }
  __syncthreads();

  float mk[4][4];
#pragma unroll
  for (int mt = 0; mt < 4; mt++) {
    int4 mv = *(const int4*)(mask + bm0 + wm0 + mt * 16 + quad * 4);
    mk[mt][0] = (float)mv.x; mk[mt][1] = (float)mv.y;
    mk[mt][2] = (float)mv.z; mk[mt][3] = (float)mv.w;
  }

  const size_t cbase = ((size_t)(by * 2 + bx)) * 32768 + (size_t)w * 4096;
#pragma unroll
  for (int nt = 0; nt < 4; nt++) {
    const int nl = wn0 + nt * 16 + l15;
    const float bias = b1[bn0 + nl];
    float ps = 0.f, pq = 0.f;
#pragma unroll
    for (int mt = 0; mt < 4; mt++) {
      ushort4 st;
      float v0 = acc[mt][nt][0] + bias;
      float v1 = acc[mt][nt][1] + bias;
      float v2 = acc[mt][nt][2] + bias;
      float v3 = acc[mt][nt][3] + bias;
      ps += v0 * mk[mt][0] + v1 * mk[mt][1] + v2 * mk[mt][2] + v3 * mk[mt][3];
      pq += v0 * v0 * mk[mt][0] + v1 * v1 * mk[mt][1] +
            v2 * v2 * mk[mt][2] + v3 * v3 * mk[mt][3];
      st.x = f2bf(v0); st.y = f2bf(v1); st.z = f2bf(v2); st.w = f2bf(v3);
      *(ushort4*)&Hout[cbase + (size_t)(mt * 4 + nt) * 256 + lane * 4] = st;
    }
    atomicAdd(&csum[nl], ps);
    atomicAdd(&csq[nl], pq);
  }

  __syncthreads();
  if (t < BN2) {
    atomicAdd(&gsum[bn0 + t], csum[t]);
    atomicAdd(&gsq[bn0 + t], csq[t]);
  }
}

// BN(finalize fused) + ReLU + masked pool over the tiled Hout layout. (r0)
__global__ __launch_bounds__(256) void bnpool_kernel(
    const unsigned short* __restrict__ Hbuf, const int* __restrict__ mask,
    const float* __restrict__ ws, const float* __restrict__ gamma,
    const float* __restrict__ beta, float* __restrict__ PH)
{
  __shared__ float mkf[BM];
  __shared__ float redc[32];
  const int t = threadIdx.x;
  const int chunk = blockIdx.x;        // 0..1023
  const int by = chunk >> 1, bx = chunk & 1;
  const int b = chunk >> 5;            // 32 chunks per batch
  if (t < 32) redc[t] = ws[OFF_CNT + t];
  if (t < BM) mkf[t] = (float)mask[by * BM + t];
  __syncthreads();

  float nv = 0.f;
#pragma unroll
  for (int i = 0; i < 32; i++) nv += redc[i];
  nv = fmaxf(nv, 1.f);
  const float inv = 1.f / nv;
  const int c = bx * BN2 + t;
  const float m = ws[OFF_S1 + c] * inv;
  const float var = ws[OFF_S2 + c] * inv - m * m;
  const float istd = rsqrtf(fmaxf(var, 0.f) + EPSC);
  const float scv = istd * gamma[c];
  const float shv = beta[c] - m * scv;

  const int w3 = t >> 6, nt = (t >> 4) & 3, l15 = t & 15;
  float acc = 0.f;
#pragma unroll
  for (int h = 0; h < 2; h++) {
    const int w = w3 + h * 4;          // same wn0 group, wm half h
    const int wm0 = h * 64;
    const unsigned short* base =
        Hbuf + (size_t)chunk * 32768 + (size_t)w * 4096 + nt * 256 + l15 * 4;
#pragma unroll
    for (int mt = 0; mt < 4; mt++)
#pragma unroll
      for (int q = 0; q < 4; q++) {
        ushort4 hv = *(const ushort4*)(base + mt * 1024 + q * 64);
        const float* mv = &mkf[wm0 + mt * 16 + q * 4];
        acc += fmaxf(fmaf(bf2f(hv.x), scv, shv), 0.f) * mv[0]
             + fmaxf(fmaf(bf2f(hv.y), scv, shv), 0.f) * mv[1]
             + fmaxf(fmaf(bf2f(hv.z), scv, shv), 0.f) * mv[2]
             + fmaxf(fmaf(bf2f(hv.w), scv, shv), 0.f) * mv[3];
      }
  }
  atomicAdd(&PH[b * Hn + c], acc);
}

// out[b][c] = (PH[b]/max(cnt,1)) @ W2[:,c] + b2[c]*(cnt/max(cnt,1))
__global__ __launch_bounds__(128) void final_kernel(
    const float* __restrict__ pooledh, const float* __restrict__ cnt,
    const float* __restrict__ W2, const float* __restrict__ b2,
    float* __restrict__ out)
{
  __shared__ float pr[Hn];
  int b = blockIdx.x >> 2;
  int cc = blockIdx.x & 3;
  int t = threadIdx.x;
  float nb = cnt[b];
  float inv = 1.f / fmaxf(nb, 1.f);
#pragma unroll
  for (int i = 0; i < 4; i++)
    pr[t + i * 128] = pooledh[b * Hn + t + i * 128] * inv;
  __syncthreads();
  int c = cc * 128 + t;
  float a0 = 0.f, a1 = 0.f, a2 = 0.f, a3 = 0.f;
  for (int i = 0; i < Hn; i += 4) {
    a0 = fmaf(pr[i],     W2[(size_t)i * Hn + c],       a0);
    a1 = fmaf(pr[i + 1], W2[(size_t)(i + 1) * Hn + c], a1);
    a2 = fmaf(pr[i + 2], W2[(size_t)(i + 2) * Hn + c], a2);
    a3 = fmaf(pr[i + 3], W2[(size_t)(i + 3) * Hn + c], a3);
  }
  out[b * Hn + c] = (a0 + a1) + (a2 + a3) + b2[c] * (nb * inv);
}

extern "C" void kernel_launch(void* const* d_in, const int* in_sizes, int n_in,
                              void* d_out, int out_size, void* d_ws, size_t ws_size,
                              hipStream_t stream) {
  const float* hidden = (const float*)d_in[0];
  const int*   mask   = (const int*)d_in[1];
  const float* W1     = (const float*)d_in[2];
  const float* b1     = (const float*)d_in[3];
  const float* gamma  = (const float*)d_in[4];
  const float* beta   = (const float*)d_in[5];
  const float* W2     = (const float*)d_in[6];
  const float* b2     = (const float*)d_in[7];
  float* out = (float*)d_out;
  float* ws  = (float*)d_ws;
  unsigned short* W1t  = (unsigned short*)((char*)d_ws + OFF_W1T_BYTES);
  unsigned short* Hbuf = (unsigned short*)((char*)d_ws + OFF_H_BYTES);

  prep_kernel<<<Bn + 1 + (Dn / 32) * (Hn / 32), 256, 0, stream>>>(
      mask, W1, W1t, ws);
  gemm1_mfma<<<dim3(Hn / BN2, Mn / BM), 512, 0, stream>>>(
      hidden, W1t, b1, mask, Hbuf, ws + OFF_S1, ws + OFF_S2);
  bnpool_kernel<<<(Mn / BM) * (Hn / BN2), 256, 0, stream>>>(
      Hbuf, mask, ws, gamma, beta, ws + OFF_PH);
  final_kernel<<<Bn * 4, 128, 0, stream>>>(ws + OFF_PH, ws + OFF_CNT, W2, b2, out);
}

// Round 10
// 367.753 us; speedup vs baseline: 1.5539x; 1.0030x over previous
//
#include <hip/hip_runtime.h>
#include <hip/hip_bf16.h>

#define Bn 32
#define Ln 2048
#define Dn 768
#define Hn 512
#define Mn (Bn*Ln)
#define EPSC 1e-5f

// ws float-offset layout (first 128 KB), then byte regions
#define OFF_S1   0        // [512] masked sum(h)
#define OFF_S2   512      // [512] masked sum(h^2)
#define OFF_CNT  2048     // [32] per-batch counts
#define OFF_PH   2304     // [32*512] pooled relu(BN(h)) sums (atomic)
#define OFF_W1T_BYTES  131072   // bf16 W1^T [512][768] = 786 KB
#define OFF_H_BYTES    1048576  // tiled bf16 h buffer, 64 MB

#define BM 128
#define BN2 256
#define BK 64
#define KT_N (Dn/BK)

typedef __attribute__((ext_vector_type(8))) short bf16x8;
typedef __attribute__((ext_vector_type(4))) float f32x4;

static __device__ __forceinline__ unsigned short f2bf(float x) {
  __hip_bfloat16 h = __float2bfloat16(x);
  return *reinterpret_cast<unsigned short*>(&h);
}
static __device__ __forceinline__ float bf2f(unsigned short u) {
  return __uint_as_float(((unsigned int)u) << 16);
}

// prep: blocks 0..31 per-batch counts; block 32 zeros S1,S2,PH;
// blocks 33..416 transpose W1 (768x512 fp32 -> 512x768 bf16). (r7/r8-verified)
__global__ __launch_bounds__(256) void prep_kernel(
    const int* __restrict__ mask, const float* __restrict__ W1,
    unsigned short* __restrict__ W1t, float* __restrict__ ws) {
  int blk = blockIdx.x, t = threadIdx.x;
  if (blk < Bn) {
    __shared__ int red[256];
    int s = 0;
#pragma unroll
    for (int i = 0; i < 8; i++) s += mask[blk * Ln + i * 256 + t];
    red[t] = s;
    __syncthreads();
    for (int off = 128; off > 0; off >>= 1) {
      if (t < off) red[t] += red[t + off];
      __syncthreads();
    }
    if (t == 0) ws[OFF_CNT + blk] = (float)red[0];
  } else if (blk == Bn) {
#pragma unroll
    for (int i = 0; i < 4; i++) ws[OFF_S1 + i * 256 + t] = 0.f;
#pragma unroll
    for (int i = 0; i < 64; i++) ws[OFF_PH + i * 256 + t] = 0.f;
  } else {
    __shared__ float tile[32][33];
    int tb = blk - (Bn + 1);          // 0..383
    int kx = (tb % 24) * 32;          // Dn/32 = 24
    int nx = (tb / 24) * 32;          // Hn/32 = 16
    int tx = t & 31, ty = t >> 5;
#pragma unroll
    for (int i = 0; i < 32; i += 8)
      tile[ty + i][tx] = W1[(size_t)(kx + ty + i) * Hn + nx + tx];
    __syncthreads();
#pragma unroll
    for (int i = 0; i < 32; i += 8)
      W1t[(size_t)(nx + ty + i) * Dn + kx + tx] = f2bf(tile[tx][ty + i]);
  }
}

// GEMM1 v9 (resubmit; r9 was an infra failure with the r1-precedent error):
// r8's winning kernel + two local fixes (no schedule change):
//  (1) As XOR-swizzled (r5-verified formulas, byte ^= ((row&7)<<4), LDK=64)
//      replacing the pad-72 path -> kills the residual 3.15M bank conflicts.
//  (2) A(kt+1) global loads issued AFTER the second barrier (inside kt's
//      MFMA phase) -> ~600-cy load latency hides under compute; next iter's
//      barrier vmcnt(0) drain absorbs arrival. Single rA set (PACK(kt)
//      precedes LOAD(kt+1) in program order; __syncthreads fences motion).
// B staging (r8-verified): gload_lds dwordx4, pre-swizzled global source.
// LDS 51.2 KB; LB(512,4). Hout layout r0-verbatim (bnpool-compatible):
//   chunk = by*2+bx; w*4096 + (mt*4+nt)*256 + lane*4 + r
__global__ __launch_bounds__(512, 4) void gemm1_mfma(
    const float* __restrict__ A, const unsigned short* __restrict__ W1t,
    const float* __restrict__ b1, const int* __restrict__ mask,
    unsigned short* __restrict__ Hout,
    float* __restrict__ gsum, float* __restrict__ gsq)
{
  __shared__ __align__(16) unsigned short As[BM * BK];     // 16 KB swizzled
  __shared__ __align__(16) unsigned short Bs[BN2 * BK];    // 32 KB swizzled
  __shared__ float csum[BN2];
  __shared__ float csq[BN2];

  const int t = threadIdx.x;
  const int bx = blockIdx.x;   // N: 0..1
  const int by = blockIdx.y;   // M: 0..511
  const int bm0 = by * BM;
  const int bn0 = bx * BN2;

  const int w = t >> 6;
  const int lane = t & 63;
  const int wm0 = (w >> 2) * 64;
  const int wn0 = (w & 3) * 64;
  const int l15 = lane & 15;
  const int quad = lane >> 4;

  // A staging map (r0): thread covers 16 consecutive floats of its row
  const int am = t >> 2;           // 0..127
  const int ak = (t & 3) * 16;     // elem col 0/16/32/48
  const float* Ap = A + (size_t)(bm0 + am) * Dn + ak;
  // swizzled byte targets (r5-verified): byte ^= ((row&7)<<4)
  const int aswz = (am & 7) << 4;
  const int ab0 = am * 128 + ((ak * 2) ^ aswz);
  const int ab1 = am * 128 + ((ak * 2 + 16) ^ aswz);

  // B staging (r5/r8-verified): phys LDS byte p holds logical tile byte
  // q = p ^ ((p>>7 & 7)<<4). Per-thread pre-swizzled global sources.
  const int p0 = ((w * 4 + 0) << 10) + (lane << 4);
  const int p1 = ((w * 4 + 1) << 10) + (lane << 4);
  const int p2 = ((w * 4 + 2) << 10) + (lane << 4);
  const int p3 = ((w * 4 + 3) << 10) + (lane << 4);
  const int q0 = p0 ^ (((p0 >> 7) & 7) << 4);
  const int q1 = p1 ^ (((p1 >> 7) & 7) << 4);
  const int q2 = p2 ^ (((p2 >> 7) & 7) << 4);
  const int q3 = p3 ^ (((p3 >> 7) & 7) << 4);
  const char* bsrc0 = (const char*)(W1t + (size_t)(bn0 + (q0 >> 7)) * Dn) + (q0 & 127);
  const char* bsrc1 = (const char*)(W1t + (size_t)(bn0 + (q1 >> 7)) * Dn) + (q1 & 127);
  const char* bsrc2 = (const char*)(W1t + (size_t)(bn0 + (q2 >> 7)) * Dn) + (q2 & 127);
  const char* bsrc3 = (const char*)(W1t + (size_t)(bn0 + (q3 >> 7)) * Dn) + (q3 & 127);

  f32x4 acc[4][4];
#pragma unroll
  for (int i = 0; i < 4; i++)
#pragma unroll
    for (int j = 0; j < 4; j++) acc[i][j] = (f32x4){0.f, 0.f, 0.f, 0.f};

  // A prefetch registers: rA holds A(kt) at the top of iteration kt.
  float4 rA0 = *(const float4*)(Ap);
  float4 rA1 = *(const float4*)(Ap + 4);
  float4 rA2 = *(const float4*)(Ap + 8);
  float4 rA3 = *(const float4*)(Ap + 12);

#pragma unroll
  for (int kt = 0; kt < KT_N; ++kt) {
    const int k0 = kt * BK;
    __syncthreads();   // prev kt's LDS reads retired; A(kt) regs arrived
    // B: 4x global_load_lds dwordx4 (LDS dest wave-uniform + lane*16 by HW)
    __builtin_amdgcn_global_load_lds(
        (const __attribute__((address_space(1))) void*)(bsrc0 + k0 * 2),
        (__attribute__((address_space(3))) void*)((char*)&Bs[0] + ((w * 4 + 0) << 10)),
        16, 0, 0);
    __builtin_amdgcn_global_load_lds(
        (const __attribute__((address_space(1))) void*)(bsrc1 + k0 * 2),
        (__attribute__((address_space(3))) void*)((char*)&Bs[0] + ((w * 4 + 1) << 10)),
        16, 0, 0);
    __builtin_amdgcn_global_load_lds(
        (const __attribute__((address_space(1))) void*)(bsrc2 + k0 * 2),
        (__attribute__((address_space(3))) void*)((char*)&Bs[0] + ((w * 4 + 2) << 10)),
        16, 0, 0);
    __builtin_amdgcn_global_load_lds(
        (const __attribute__((address_space(1))) void*)(bsrc3 + k0 * 2),
        (__attribute__((address_space(3))) void*)((char*)&Bs[0] + ((w * 4 + 3) << 10)),
        16, 0, 0);
    // A: cvt + pack + swizzled ds_write (consumes rA = A(kt))
    {
      uint4 w0, w1;
      w0.x = (unsigned)f2bf(rA0.x) | ((unsigned)f2bf(rA0.y) << 16);
      w0.y = (unsigned)f2bf(rA0.z) | ((unsigned)f2bf(rA0.w) << 16);
      w0.z = (unsigned)f2bf(rA1.x) | ((unsigned)f2bf(rA1.y) << 16);
      w0.w = (unsigned)f2bf(rA1.z) | ((unsigned)f2bf(rA1.w) << 16);
      w1.x = (unsigned)f2bf(rA2.x) | ((unsigned)f2bf(rA2.y) << 16);
      w1.y = (unsigned)f2bf(rA2.z) | ((unsigned)f2bf(rA2.w) << 16);
      w1.z = (unsigned)f2bf(rA3.x) | ((unsigned)f2bf(rA3.y) << 16);
      w1.w = (unsigned)f2bf(rA3.z) | ((unsigned)f2bf(rA3.w) << 16);
      *(uint4*)((char*)&As[0] + ab0) = w0;
      *(uint4*)((char*)&As[0] + ab1) = w1;
    }
    __syncthreads();   // implicit vmcnt(0)+lgkm(0): Bs landed, As visible
    // issue A(kt+1) now -> latency hides under the MFMA/ds_read phase;
    // next iteration's barrier drain absorbs arrival.
    if (kt < KT_N - 1) {
      rA0 = *(const float4*)(Ap + k0 + BK);
      rA1 = *(const float4*)(Ap + k0 + BK + 4);
      rA2 = *(const float4*)(Ap + k0 + BK + 8);
      rA3 = *(const float4*)(Ap + k0 + BK + 12);
    }
#pragma unroll
    for (int s = 0; s < 2; s++) {
      bf16x8 af[4], bf[4];
#pragma unroll
      for (int mt = 0; mt < 4; mt++) {
        const int ra = wm0 + mt * 16 + l15;
        const int ca = (s * 64 + quad * 16) ^ ((ra & 7) << 4);
        af[mt] = *(const bf16x8*)((const char*)&As[0] + ra * 128 + ca);
      }
#pragma unroll
      for (int nt = 0; nt < 4; nt++) {
        const int rb = wn0 + nt * 16 + l15;
        const int cb = (s * 64 + quad * 16) ^ ((rb & 7) << 4);
        bf[nt] = *(const bf16x8*)((const char*)&Bs[0] + rb * 128 + cb);
      }
#pragma unroll
      for (int mt = 0; mt < 4; mt++)
#pragma unroll
        for (int nt = 0; nt < 4; nt++)
          acc[mt][nt] = __builtin_amdgcn_mfma_f32_16x16x32_bf16(
              af[mt], bf[nt], acc[mt][nt], 0, 0, 0);
    }
  }

  // ---- epilogue: bias, masked stats, coalesced tiled bf16 store (r0) ----
  if (t < BN2) { csum[t] = 0.f; csq[t] = 0.f; }
  __syncthreads();

  float mk[4][4];
#pragma unroll
  for (int mt = 0; mt < 4; mt++) {
    int4 mv = *(const int4*)(mask + bm0 + wm0 + mt * 16 + quad * 4);
    mk[mt][0] = (float)mv.x; mk[mt][1] = (float)mv.y;
    mk[mt][2] = (float)mv.z; mk[mt][3] = (float)mv.w;
  }

  const size_t cbase = ((size_t)(by * 2 + bx)) * 32768 + (size_t)w * 4096;
#pragma unroll
  for (int nt = 0; nt < 4; nt++) {
    const int nl = wn0 + nt * 16 + l15;
    const float bias = b1[bn0 + nl];
    float ps = 0.f, pq = 0.f;
#pragma unroll
    for (int mt = 0; mt < 4; mt++) {
      ushort4 st;
      float v0 = acc[mt][nt][0] + bias;
      float v1 = acc[mt][nt][1] + bias;
      float v2 = acc[mt][nt][2] + bias;
      float v3 = acc[mt][nt][3] + bias;
      ps += v0 * mk[mt][0] + v1 * mk[mt][1] + v2 * mk[mt][2] + v3 * mk[mt][3];
      pq += v0 * v0 * mk[mt][0] + v1 * v1 * mk[mt][1] +
            v2 * v2 * mk[mt][2] + v3 * v3 * mk[mt][3];
      st.x = f2bf(v0); st.y = f2bf(v1); st.z = f2bf(v2); st.w = f2bf(v3);
      *(ushort4*)&Hout[cbase + (size_t)(mt * 4 + nt) * 256 + lane * 4] = st;
    }
    atomicAdd(&csum[nl], ps);
    atomicAdd(&csq[nl], pq);
  }

  __syncthreads();
  if (t < BN2) {
    atomicAdd(&gsum[bn0 + t], csum[t]);
    atomicAdd(&gsq[bn0 + t], csq[t]);
  }
}

// BN(finalize fused) + ReLU + masked pool over the tiled Hout layout. (r0)
__global__ __launch_bounds__(256) void bnpool_kernel(
    const unsigned short* __restrict__ Hbuf, const int* __restrict__ mask,
    const float* __restrict__ ws, const float* __restrict__ gamma,
    const float* __restrict__ beta, float* __restrict__ PH)
{
  __shared__ float mkf[BM];
  __shared__ float redc[32];
  const int t = threadIdx.x;
  const int chunk = blockIdx.x;        // 0..1023
  const int by = chunk >> 1, bx = chunk & 1;
  const int b = chunk >> 5;            // 32 chunks per batch
  if (t < 32) redc[t] = ws[OFF_CNT + t];
  if (t < BM) mkf[t] = (float)mask[by * BM + t];
  __syncthreads();

  float nv = 0.f;
#pragma unroll
  for (int i = 0; i < 32; i++) nv += redc[i];
  nv = fmaxf(nv, 1.f);
  const float inv = 1.f / nv;
  const int c = bx * BN2 + t;
  const float m = ws[OFF_S1 + c] * inv;
  const float var = ws[OFF_S2 + c] * inv - m * m;
  const float istd = rsqrtf(fmaxf(var, 0.f) + EPSC);
  const float scv = istd * gamma[c];
  const float shv = beta[c] - m * scv;

  const int w3 = t >> 6, nt = (t >> 4) & 3, l15 = t & 15;
  float acc = 0.f;
#pragma unroll
  for (int h = 0; h < 2; h++) {
    const int w = w3 + h * 4;          // same wn0 group, wm half h
    const int wm0 = h * 64;
    const unsigned short* base =
        Hbuf + (size_t)chunk * 32768 + (size_t)w * 4096 + nt * 256 + l15 * 4;
#pragma unroll
    for (int mt = 0; mt < 4; mt++)
#pragma unroll
      for (int q = 0; q < 4; q++) {
        ushort4 hv = *(const ushort4*)(base + mt * 1024 + q * 64);
        const float* mv = &mkf[wm0 + mt * 16 + q * 4];
        acc += fmaxf(fmaf(bf2f(hv.x), scv, shv), 0.f) * mv[0]
             + fmaxf(fmaf(bf2f(hv.y), scv, shv), 0.f) * mv[1]
             + fmaxf(fmaf(bf2f(hv.z), scv, shv), 0.f) * mv[2]
             + fmaxf(fmaf(bf2f(hv.w), scv, shv), 0.f) * mv[3];
      }
  }
  atomicAdd(&PH[b * Hn + c], acc);
}

// out[b][c] = (PH[b]/max(cnt,1)) @ W2[:,c] + b2[c]*(cnt/max(cnt,1))
__global__ __launch_bounds__(128) void final_kernel(
    const float* __restrict__ pooledh, const float* __restrict__ cnt,
    const float* __restrict__ W2, const float* __restrict__ b2,
    float* __restrict__ out)
{
  __shared__ float pr[Hn];
  int b = blockIdx.x >> 2;
  int cc = blockIdx.x & 3;
  int t = threadIdx.x;
  float nb = cnt[b];
  float inv = 1.f / fmaxf(nb, 1.f);
#pragma unroll
  for (int i = 0; i < 4; i++)
    pr[t + i * 128] = pooledh[b * Hn + t + i * 128] * inv;
  __syncthreads();
  int c = cc * 128 + t;
  float a0 = 0.f, a1 = 0.f, a2 = 0.f, a3 = 0.f;
  for (int i = 0; i < Hn; i += 4) {
    a0 = fmaf(pr[i],     W2[(size_t)i * Hn + c],       a0);
    a1 = fmaf(pr[i + 1], W2[(size_t)(i + 1) * Hn + c], a1);
    a2 = fmaf(pr[i + 2], W2[(size_t)(i + 2) * Hn + c], a2);
    a3 = fmaf(pr[i + 3], W2[(size_t)(i + 3) * Hn + c], a3);
  }
  out[b * Hn + c] = (a0 + a1) + (a2 + a3) + b2[c] * (nb * inv);
}

extern "C" void kernel_launch(void* const* d_in, const int* in_sizes, int n_in,
                              void* d_out, int out_size, void* d_ws, size_t ws_size,
                              hipStream_t stream) {
  const float* hidden = (const float*)d_in[0];
  const int*   mask   = (const int*)d_in[1];
  const float* W1     = (const float*)d_in[2];
  const float* b1     = (const float*)d_in[3];
  const float* gamma  = (const float*)d_in[4];
  const float* beta   = (const float*)d_in[5];
  const float* W2     = (const float*)d_in[6];
  const float* b2     = (const float*)d_in[7];
  float* out = (float*)d_out;
  float* ws  = (float*)d_ws;
  unsigned short* W1t  = (unsigned short*)((char*)d_ws + OFF_W1T_BYTES);
  unsigned short* Hbuf = (unsigned short*)((char*)d_ws + OFF_H_BYTES);

  prep_kernel<<<Bn + 1 + (Dn / 32) * (Hn / 32), 256, 0, stream>>>(
      mask, W1, W1t, ws);
  gemm1_mfma<<<dim3(Hn / BN2, Mn / BM), 512, 0, stream>>>(
      hidden, W1t, b1, mask, Hbuf, ws + OFF_S1, ws + OFF_S2);
  bnpool_kernel<<<(Mn / BM) * (Hn / BN2), 256, 0, stream>>>(
      Hbuf, mask, ws, gamma, beta, ws + OFF_PH);
  final_kernel<<<Bn * 4, 128, 0, stream>>>(ws + OFF_PH, ws + OFF_CNT, W2, b2, out);
}